// Round 1
// baseline (94.982 us; speedup 1.0000x reference)
//
#include <hip/hip_runtime.h>

#define OUTN 512
#define NCTL 64
#define BATCH 16
#define WPB 4   // waves per block; each wave owns one (b,u) output row

// Grid: (OUTN/WPB, BATCH), 256 threads.
// Per wave (one u-row):
//   Phase 1: lane n loads float4 ctrl[b][su-3+r][n][:] for r=0..3 (4 dense 1KB
//            wave-loads), contracts with Nu -> A[n][0..3], one ds_write_b128.
//   Phase 2: lane handles v = 8*lane .. 8*lane+7; per point 4x ds_read_b128
//            from its wave's A slice, 16 FMA, v_rcp; packs 8 points (96B
//            contiguous) into 6 float4 stores.
__global__ __launch_bounds__(256, 4) void surfeval_kernel(
    const float* __restrict__ ctrl,   // (B,64,64,4)
    const int*   __restrict__ uspan,  // (512)
    const int*   __restrict__ vspan,  // (512)
    const float* __restrict__ Nu,     // (512,4)
    const float* __restrict__ Nv,     // (512,4)
    float*       __restrict__ out)    // (B,512,512,3)
{
    __shared__ float A[WPB][NCTL * 4];   // 4 KB, 1 KB slice per wave

    const int t    = threadIdx.x;
    const int wave = t >> 6;
    const int lane = t & 63;
    const int b    = blockIdx.y;
    // u is wave-uniform: force into SGPR so uspan/Nu become scalar loads
    const int u    = __builtin_amdgcn_readfirstlane(blockIdx.x * WPB + wave);

    // ---- per-lane phase-2 operands (independent of phase 1; issue first) ----
    const int  vbase = lane << 3;                       // first of 8 v-points
    const int4 sva = ((const int4*)vspan)[(lane << 1) | 0];
    const int4 svb = ((const int4*)vspan)[(lane << 1) | 1];
    float4 nv[8];
    #pragma unroll
    for (int i = 0; i < 8; ++i) nv[i] = ((const float4*)Nv)[vbase + i];
    const int sv[8] = {sva.x, sva.y, sva.z, sva.w, svb.x, svb.y, svb.z, svb.w};

    // ---- phase 1: A[n][c] = sum_r Nu[u][r] * ctrl[b][su-3+r][n][c] ----
    const int    su = uspan[u];
    const float4 nu = ((const float4*)Nu)[u];
    const float4* crow = (const float4*)ctrl
                       + (size_t)(b * NCTL + (su - 3)) * NCTL + lane;
    const float4 r0 = crow[0];
    const float4 r1 = crow[NCTL];
    const float4 r2 = crow[2 * NCTL];
    const float4 r3 = crow[3 * NCTL];
    float4 a;
    a.x = nu.x * r0.x + nu.y * r1.x + nu.z * r2.x + nu.w * r3.x;
    a.y = nu.x * r0.y + nu.y * r1.y + nu.z * r2.y + nu.w * r3.y;
    a.z = nu.x * r0.z + nu.y * r1.z + nu.z * r2.z + nu.w * r3.z;
    a.w = nu.x * r0.w + nu.y * r1.w + nu.z * r2.w + nu.w * r3.w;
    ((float4*)A[wave])[lane] = a;
    __syncthreads();   // conservative; each wave only reads its own slice

    // ---- phase 2: 8 v-points per lane, 96B contiguous output ----
    float* __restrict__ orow = out + ((size_t)(b * OUTN + u)) * (OUTN * 3)
                             + (size_t)vbase * 3;
    const float* Aw = A[wave];
    float4 o0, o1, o2;
    #pragma unroll
    for (int i = 0; i < 8; ++i) {
        const float4* Af = (const float4*)(Aw + ((sv[i] - 3) << 2));
        const float4 s0 = Af[0], s1 = Af[1], s2 = Af[2], s3 = Af[3];
        const float4 n  = nv[i];
        const float sx = n.x * s0.x + n.y * s1.x + n.z * s2.x + n.w * s3.x;
        const float sy = n.x * s0.y + n.y * s1.y + n.z * s2.y + n.w * s3.y;
        const float sz = n.x * s0.z + n.y * s1.z + n.z * s2.z + n.w * s3.z;
        const float sw = n.x * s0.w + n.y * s1.w + n.z * s2.w + n.w * s3.w;
        const float inv = __builtin_amdgcn_rcpf(sw);   // |rel err| ~1e-6 << tol
        const float rx = sx * inv, ry = sy * inv, rz = sz * inv;
        const int j = i & 3;               // compile-time after unroll
        if (j == 0)      { o0.x = rx; o0.y = ry; o0.z = rz; }
        else if (j == 1) { o0.w = rx; o1.x = ry; o1.y = rz; }
        else if (j == 2) { o1.z = rx; o1.w = ry; o2.x = rz; }
        else {
            o2.y = rx; o2.z = ry; o2.w = rz;
            float4* og = (float4*)orow + (i >> 2) * 3;
            og[0] = o0; og[1] = o1; og[2] = o2;
        }
    }
}

extern "C" void kernel_launch(void* const* d_in, const int* in_sizes, int n_in,
                              void* d_out, int out_size, void* d_ws, size_t ws_size,
                              hipStream_t stream) {
    const float* ctrl  = (const float*)d_in[0];
    const int*   uspan = (const int*)d_in[1];
    const int*   vspan = (const int*)d_in[2];
    const float* Nu    = (const float*)d_in[3];
    const float* Nv    = (const float*)d_in[4];
    float* out = (float*)d_out;

    dim3 grid(OUTN / WPB, BATCH);   // (128, 16) = 2048 blocks
    surfeval_kernel<<<grid, 256, 0, stream>>>(ctrl, uspan, vspan, Nu, Nv, out);
}

// Round 2
// 80.272 us; speedup vs baseline: 1.1833x; 1.1833x over previous
//
#include <hip/hip_runtime.h>

#define OUTN 512
#define NCTL 64
#define BATCH 16

// One block per (b,u) output row, 256 threads, 2 v-points per thread
// (v = t and t+256: 8 adjacent lanes share a vspan -> A-reads broadcast,
//  conflict-free).
// Phase 1: A[n][c] = sum_r Nu[u][r] * ctrl[b][su-3+r][n][c]   (LDS, 1 KB)
// Phase 2: per v: Sw[c] = sum_s Nv[v][s]*A[vspan[v]-3+s][c]; xyz*rcp(w)
//          -> staged into S[512*3] (dword-stride-3 writes: 2-way alias, free)
// Phase 3: dense writeback, lane t stores float4 t -> 1024 B/wave-instr.
__global__ __launch_bounds__(256) void surfeval_kernel(
    const float* __restrict__ ctrl,   // (B,64,64,4)
    const int*   __restrict__ uspan,  // (512)
    const int*   __restrict__ vspan,  // (512)
    const float* __restrict__ Nu,     // (512,4)
    const float* __restrict__ Nv,     // (512,4)
    float*       __restrict__ out)    // (B,512,512,3)
{
    __shared__ float A[NCTL][4];    // 1 KB
    __shared__ float S[OUTN * 3];   // 6 KB staged output row

    const int t = threadIdx.x;
    const int u = blockIdx.x;
    const int b = blockIdx.y;

    // ---- Prefetch phase-2 inputs early (independent of phase 1) ----
    const int v0 = t;
    const int v1 = t + 256;
    const int sv0 = vspan[v0];
    const int sv1 = vspan[v1];
    const float4 nv0 = ((const float4*)Nv)[v0];
    const float4 nv1 = ((const float4*)Nv)[v1];

    // ---- Phase 1: contract over u-direction into A ----
    const int su = uspan[u];
    const float4 nu = ((const float4*)Nu)[u];
    {
        // thread t -> element t of each of 4 contiguous ctrl rows (1 KB
        // coalesced per row-load)
        const float* p = ctrl + ((size_t)b * NCTL + (size_t)(su - 3)) * (NCTL * 4) + t;
        A[t >> 2][t & 3] = nu.x * p[0]
                         + nu.y * p[NCTL * 4]
                         + nu.z * p[2 * NCTL * 4]
                         + nu.w * p[3 * NCTL * 4];
    }
    __syncthreads();

    // ---- Phase 2: compute 2 points, stage into S ----
    {
        const float4* Af = (const float4*)(&A[sv0 - 3][0]);
        const float4 s0 = Af[0], s1 = Af[1], s2 = Af[2], s3 = Af[3];
        const float sx = nv0.x * s0.x + nv0.y * s1.x + nv0.z * s2.x + nv0.w * s3.x;
        const float sy = nv0.x * s0.y + nv0.y * s1.y + nv0.z * s2.y + nv0.w * s3.y;
        const float sz = nv0.x * s0.z + nv0.y * s1.z + nv0.z * s2.z + nv0.w * s3.z;
        const float sw = nv0.x * s0.w + nv0.y * s1.w + nv0.z * s2.w + nv0.w * s3.w;
        const float inv = __builtin_amdgcn_rcpf(sw);   // rel err ~1e-6 << 7.8e-3 tol
        S[3 * v0 + 0] = sx * inv;
        S[3 * v0 + 1] = sy * inv;
        S[3 * v0 + 2] = sz * inv;
    }
    {
        const float4* Af = (const float4*)(&A[sv1 - 3][0]);
        const float4 s0 = Af[0], s1 = Af[1], s2 = Af[2], s3 = Af[3];
        const float sx = nv1.x * s0.x + nv1.y * s1.x + nv1.z * s2.x + nv1.w * s3.x;
        const float sy = nv1.x * s0.y + nv1.y * s1.y + nv1.z * s2.y + nv1.w * s3.y;
        const float sz = nv1.x * s0.z + nv1.y * s1.z + nv1.z * s2.z + nv1.w * s3.z;
        const float sw = nv1.x * s0.w + nv1.y * s1.w + nv1.z * s2.w + nv1.w * s3.w;
        const float inv = __builtin_amdgcn_rcpf(sw);
        S[3 * v1 + 0] = sx * inv;
        S[3 * v1 + 1] = sy * inv;
        S[3 * v1 + 2] = sz * inv;
    }
    __syncthreads();

    // ---- Phase 3: dense coalesced writeback (384 float4s) ----
    float4* __restrict__ og = (float4*)(out + ((size_t)b * OUTN + (size_t)u) * (OUTN * 3));
    const float4* Sf = (const float4*)S;
    og[t] = Sf[t];
    if (t < (OUTN * 3 / 4) - 256) {          // 128 remaining; waves 0-1, uniform
        og[256 + t] = Sf[256 + t];
    }
}

extern "C" void kernel_launch(void* const* d_in, const int* in_sizes, int n_in,
                              void* d_out, int out_size, void* d_ws, size_t ws_size,
                              hipStream_t stream) {
    const float* ctrl  = (const float*)d_in[0];
    const int*   uspan = (const int*)d_in[1];
    const int*   vspan = (const int*)d_in[2];
    const float* Nu    = (const float*)d_in[3];
    const float* Nv    = (const float*)d_in[4];
    float* out = (float*)d_out;

    dim3 grid(OUTN, BATCH);   // 8192 blocks
    surfeval_kernel<<<grid, 256, 0, stream>>>(ctrl, uspan, vspan, Nu, Nv, out);
}

// Round 3
// 79.795 us; speedup vs baseline: 1.1903x; 1.0060x over previous
//
#include <hip/hip_runtime.h>

#define OUTN 512
#define NCTL 64
#define BATCH 16
#define ROWS 4   // u-rows per block

// Grid (OUTN/ROWS, BATCH) = (128,16) = 2048 blocks, 256 threads.
// Each block computes ROWS consecutive u-rows for one batch b.
// v-side operands (vspan, Nv) are loaded ONCE per thread and reused for all
// ROWS rows; one barrier total; 16 independent phase-1 loads issue together.
// Lane=v mapping keeps phase-2 LDS reads broadcast/conflict-free (8 adjacent
// lanes share a vspan; distinct addresses cover banks 0..31 exactly once).
__global__ __launch_bounds__(256) void surfeval_kernel(
    const float* __restrict__ ctrl,   // (B,64,64,4)
    const int*   __restrict__ uspan,  // (512)
    const int*   __restrict__ vspan,  // (512)
    const float* __restrict__ Nu,     // (512,4)
    const float* __restrict__ Nv,     // (512,4)
    float*       __restrict__ out)    // (B,512,512,3)
{
    __shared__ float A[ROWS][NCTL][4];   // 4 KB

    const int t  = threadIdx.x;
    const int u0 = blockIdx.x * ROWS;
    const int b  = blockIdx.y;

    // ---- v-side operands: load once, reuse for all ROWS rows ----
    const int v0 = t;
    const int v1 = t + 256;
    const int sv0 = vspan[v0];
    const int sv1 = vspan[v1];
    const float4 nv0 = ((const float4*)Nv)[v0];
    const float4 nv1 = ((const float4*)Nv)[v1];

    // ---- Phase 1: A[j][n][c] = sum_r Nu[u0+j][r]*ctrl[b][su_j-3+r][n][c] ----
    // 16 independent coalesced loads (4 rows x 4 taps) -> deep MLP.
    const float* cbase = ctrl + (size_t)b * (NCTL * NCTL * 4) + t;
    #pragma unroll
    for (int j = 0; j < ROWS; ++j) {
        const int    su = uspan[u0 + j];             // uniform -> s_load
        const float4 nu = ((const float4*)Nu)[u0 + j];
        const float* p  = cbase + (size_t)(su - 3) * (NCTL * 4);
        A[j][t >> 2][t & 3] = nu.x * p[0]
                            + nu.y * p[NCTL * 4]
                            + nu.z * p[2 * NCTL * 4]
                            + nu.w * p[3 * NCTL * 4];
    }
    __syncthreads();

    // ---- Phase 2: 2 v-points x ROWS rows per thread ----
    float* __restrict__ obase = out + ((size_t)(b * OUTN + u0)) * (OUTN * 3);
    #pragma unroll
    for (int j = 0; j < ROWS; ++j) {
        const float* Aj = &A[j][0][0];
        float* __restrict__ orow = obase + (size_t)j * (OUTN * 3);
        {
            const float4* Af = (const float4*)(Aj + ((sv0 - 3) << 2));
            const float4 s0 = Af[0], s1 = Af[1], s2 = Af[2], s3 = Af[3];
            const float sx = nv0.x * s0.x + nv0.y * s1.x + nv0.z * s2.x + nv0.w * s3.x;
            const float sy = nv0.x * s0.y + nv0.y * s1.y + nv0.z * s2.y + nv0.w * s3.y;
            const float sz = nv0.x * s0.z + nv0.y * s1.z + nv0.z * s2.z + nv0.w * s3.z;
            const float sw = nv0.x * s0.w + nv0.y * s1.w + nv0.z * s2.w + nv0.w * s3.w;
            const float inv = __builtin_amdgcn_rcpf(sw);  // rel err ~1e-6 << tol
            orow[v0 * 3 + 0] = sx * inv;
            orow[v0 * 3 + 1] = sy * inv;
            orow[v0 * 3 + 2] = sz * inv;
        }
        {
            const float4* Af = (const float4*)(Aj + ((sv1 - 3) << 2));
            const float4 s0 = Af[0], s1 = Af[1], s2 = Af[2], s3 = Af[3];
            const float sx = nv1.x * s0.x + nv1.y * s1.x + nv1.z * s2.x + nv1.w * s3.x;
            const float sy = nv1.x * s0.y + nv1.y * s1.y + nv1.z * s2.y + nv1.w * s3.y;
            const float sz = nv1.x * s0.z + nv1.y * s1.z + nv1.z * s2.z + nv1.w * s3.z;
            const float sw = nv1.x * s0.w + nv1.y * s1.w + nv1.z * s2.w + nv1.w * s3.w;
            const float inv = __builtin_amdgcn_rcpf(sw);
            orow[v1 * 3 + 0] = sx * inv;
            orow[v1 * 3 + 1] = sy * inv;
            orow[v1 * 3 + 2] = sz * inv;
        }
    }
}

extern "C" void kernel_launch(void* const* d_in, const int* in_sizes, int n_in,
                              void* d_out, int out_size, void* d_ws, size_t ws_size,
                              hipStream_t stream) {
    const float* ctrl  = (const float*)d_in[0];
    const int*   uspan = (const int*)d_in[1];
    const int*   vspan = (const int*)d_in[2];
    const float* Nu    = (const float*)d_in[3];
    const float* Nv    = (const float*)d_in[4];
    float* out = (float*)d_out;

    dim3 grid(OUTN / ROWS, BATCH);   // 2048 blocks -> 8/CU, one generation
    surfeval_kernel<<<grid, 256, 0, stream>>>(ctrl, uspan, vspan, Nu, Nv, out);
}